// Round 21
// baseline (204.950 us; speedup 1.0000x reference)
//
#include <hip/hip_runtime.h>
#include <math.h>

#define HF   128  // hidden width
#define CAPW 64   // ushort slots per node (Poisson(16): P(outdeg>64) ~ 1e-18)
#define HB   64   // hist blocks per (branch, keytype)

// ================= phase 1: block-private LDS histograms (1-pass, 50KB) =================
__global__ __launch_bounds__(256) void hist_kernel(const int* __restrict__ s0, const int* __restrict__ d0,
                                                   const int* __restrict__ s1, const int* __restrict__ d1,
                                                   unsigned int* __restrict__ cntbuf,
                                                   int N, int E){
  __shared__ unsigned int sm32[12544];                 // 50176 B >= N bytes
  const int t = threadIdx.x;
  const int HW = (N + 3) >> 2;
  const int b  = blockIdx.x & 63;
  const int br = (blockIdx.x >> 6) & 1;
  const int z  = blockIdx.x >> 7;
  const int* keys = z ? (br ? d1 : d0) : (br ? s1 : s0);
  for (int w = t; w < HW; w += 256) sm32[w] = 0u;
  __syncthreads();
  const int C  = (E + HB - 1) / HB;
  const int lo = b * C;
  int hi = lo + C; if (hi > E) hi = E;
  for (int i = lo + t; i < hi; i += 256){
    int k = keys[i];
    atomicAdd(&sm32[k >> 2], 1u << ((k & 3) << 3));
  }
  __syncthreads();
  unsigned int* out = cntbuf + ((size_t)(z * 2 + br) * HB + b) * HW;
  for (int w = t; w < HW; w += 256) out[w] = sm32[w];
}

// ====== phase 2: per-key reduce + prefix (no atomics); block 0 zeroes S+G (full padded span) ======
__global__ __launch_bounds__(256) void scan_kernel(unsigned int* __restrict__ cntbuf,
                                                   int* __restrict__ deg,
                                                   int* __restrict__ fill,
                                                   double* __restrict__ SG, int N){
  if (blockIdx.x == 0){
    // S pads to 256 B (32 doubles) before G(1024 doubles): zero 32+1024 = 1056 doubles.
    for (int z = threadIdx.x; z < 1056; z += 256) SG[z] = 0.0;
  }
  int k = blockIdx.x * 256 + threadIdx.x;
  if (k >= 2 * N) return;
  const int br = k >= N;
  const int kk = k - br * N;
  const int HW = (N + 3) >> 2;
  unsigned char* cb = (unsigned char*)cntbuf;
  size_t dbase = ((size_t)(2 + br) * HB) * HW * 4 + kk;
  int ds = 0;
  for (int b = 0; b < HB; ++b) ds += cb[dbase + (size_t)b * HW * 4];
  deg[k] = ds;
  size_t sbase = ((size_t)(0 + br) * HB) * HW * 4 + kk;
  int run = 0;
  for (int b = 0; b < HB; ++b){
    size_t a = sbase + (size_t)b * HW * 4;
    int c = cb[a];
    cb[a] = (unsigned char)run;
    run += c;
  }
  fill[k] = run;
}

// ================= phase 3: scatter, 256 blocks via key-range halves (25KB LDS) =================
__global__ __launch_bounds__(256) void scatter_kernel(const int* __restrict__ s0, const int* __restrict__ d0,
                                                      const int* __restrict__ s1, const int* __restrict__ d1,
                                                      const unsigned int* __restrict__ cntbuf,
                                                      unsigned short* __restrict__ slots,
                                                      int N, int E){
  __shared__ unsigned int sm32[6272];                  // 25088 B: half-range offsets
  const int t  = threadIdx.x;
  const int b  = blockIdx.x & 63;
  const int br = (blockIdx.x >> 6) & 1;
  const int h  = blockIdx.x >> 7;
  const int HW = (N + 3) >> 2;
  const int HN = ((N + 7) >> 3) << 2;                  // keys in half 0 (multiple of 4)
  const int klo = h ? HN : 0;
  const int khi = h ? N : HN;
  const int nw  = (khi - klo + 3) >> 2;
  const unsigned int* offw = cntbuf + ((size_t)br * HB + b) * HW + (klo >> 2);
  for (int w = t; w < nw; w += 256) sm32[w] = offw[w];
  __syncthreads();
  const int* srcA = br ? s1 : s0;
  const int* dstA = br ? d1 : d0;
  const int C  = (E + HB - 1) / HB;
  const int lo = b * C;
  int hi = lo + C; if (hi > E) hi = E;
  const size_t obase = (size_t)br * N;
  for (int i = lo + t; i < hi; i += 256){
    int s = srcA[i];
    if (s < klo || s >= khi) continue;
    int d = dstA[i];
    int sl = s - klo;
    unsigned int old = atomicAdd(&sm32[sl >> 2], 1u << ((sl & 3) << 3));
    int j = (old >> ((sl & 3) << 3)) & 0xff;
    if (j < CAPW) slots[(obase + s) * CAPW + j] = (unsigned short)d;
  }
}

// ====== branch0 GEMM-acc body: K=128, BK=32, conflict-free; stores h0 + k=0 colsum partial ======
__device__ __forceinline__ void gemmacc128(const float* __restrict__ A,
                                           const float* __restrict__ W,
                                           const float* __restrict__ bias,
                                           float* __restrict__ h0,
                                           float* __restrict__ partial,
                                           int rb, int N, float* smemf){
  float (*As)[68]   = (float(*)[68])smemf;
  float (*Bs)[132]  = (float(*)[132])(smemf + 2176);
  float (*red)[128] = (float(*)[128])smemf;
  const int t  = threadIdx.x;
  const int tx = t & 15;
  const int ty = t >> 4;
  const int rowbase = rb << 6;

  float acc[4][8];
  #pragma unroll
  for (int i = 0; i < 4; ++i)
    #pragma unroll
    for (int j = 0; j < 8; ++j) acc[i][j] = 0.f;

  const int ar = t >> 2;
  const int ac = (t & 3) << 2;
  const int arow = rowbase + ar;
  const int bk0 = t >> 5;
  const int bc0 = (t & 31) << 2;

  for (int k0 = 0; k0 < 128; k0 += 32){
    __syncthreads();
    float4 av0 = make_float4(0.f,0.f,0.f,0.f), av1 = make_float4(0.f,0.f,0.f,0.f);
    if (arow < N){
      av0 = *(const float4*)&A[(size_t)arow * 128 + (k0 + ac)];
      av1 = *(const float4*)&A[(size_t)arow * 128 + (k0 + 16 + ac)];
    }
    As[ac + 0][ar]      = av0.x; As[ac + 1][ar]      = av0.y;
    As[ac + 2][ar]      = av0.z; As[ac + 3][ar]      = av0.w;
    As[16 + ac + 0][ar] = av1.x; As[16 + ac + 1][ar] = av1.y;
    As[16 + ac + 2][ar] = av1.z; As[16 + ac + 3][ar] = av1.w;
    #pragma unroll
    for (int r = 0; r < 4; ++r)
      *(float4*)&Bs[bk0 + 8*r][bc0] =
        *(const float4*)&W[(size_t)(k0 + bk0 + 8*r) * HF + bc0];
    __syncthreads();
    #pragma unroll
    for (int kk = 0; kk < 32; ++kk){
      const float4 a  = *(const float4*)&As[kk][ty << 2];
      const float4 p0 = *(const float4*)&Bs[kk][tx << 2];
      const float4 p1 = *(const float4*)&Bs[kk][64 + (tx << 2)];
      const float aa[4] = {a.x, a.y, a.z, a.w};
      const float bb[8] = {p0.x, p0.y, p0.z, p0.w, p1.x, p1.y, p1.z, p1.w};
      #pragma unroll
      for (int i = 0; i < 4; ++i)
        #pragma unroll
        for (int j = 0; j < 8; ++j)
          acc[i][j] = fmaf(aa[i], bb[j], acc[i][j]);
    }
  }

  const float4 bia0 = *(const float4*)&bias[tx << 2];
  const float4 bia1 = *(const float4*)&bias[64 + (tx << 2)];
  const float bb0[8] = {bia0.x, bia0.y, bia0.z, bia0.w, bia1.x, bia1.y, bia1.z, bia1.w};
  float o[4][8];
  float cw[8];
  #pragma unroll
  for (int j = 0; j < 8; ++j) cw[j] = 0.f;
  #pragma unroll
  for (int i = 0; i < 4; ++i){
    int row = rowbase + (ty << 2) + i;
    bool valid = row < N;
    #pragma unroll
    for (int j = 0; j < 8; ++j){
      o[i][j] = 0.125f * __cosf(acc[i][j] + bb0[j]);
      if (valid) cw[j] += o[i][j];
    }
    if (valid){
      *(float4*)&h0[(size_t)row * HF + (tx << 2)]      = make_float4(o[i][0], o[i][1], o[i][2], o[i][3]);
      *(float4*)&h0[(size_t)row * HF + 64 + (tx << 2)] = make_float4(o[i][4], o[i][5], o[i][6], o[i][7]);
    }
  }
  __syncthreads();
  #pragma unroll
  for (int j = 0; j < 4; ++j){
    red[ty][(tx << 2) + j]      = cw[j];
    red[ty][64 + (tx << 2) + j] = cw[4 + j];
  }
  __syncthreads();
  for (int off = 8; off; off >>= 1){
    if (ty < off){
      #pragma unroll
      for (int j = 0; j < 4; ++j){
        red[ty][(tx << 2) + j]      += red[ty + off][(tx << 2) + j];
        red[ty][64 + (tx << 2) + j] += red[ty + off][64 + (tx << 2) + j];
      }
    }
    __syncthreads();
  }
  if (ty == 0){
    #pragma unroll
    for (int j = 0; j < 4; ++j){
      partial[(size_t)rb * 512 + (tx << 2) + j]      = red[0][(tx << 2) + j];
      partial[(size_t)rb * 512 + 64 + (tx << 2) + j] = red[0][64 + (tx << 2) + j];
    }
  }
}

// ====== pullgemm<PHASE>: pull role (blocks [0,pullBlocks)) || branch0 GEMM-acc chunk ======
template<int PHASE>
__global__ __launch_bounds__(256) void pullgemm_kernel(const float* __restrict__ A0,
                                                       const float* __restrict__ W0,
                                                       const float* __restrict__ b0,
                                                       const unsigned short* __restrict__ slots,
                                                       const int* __restrict__ fill,
                                                       const int* __restrict__ deg,
                                                       float* __restrict__ w1, float* __restrict__ qa,
                                                       float* __restrict__ qb,
                                                       float* __restrict__ w2, float* __restrict__ w3,
                                                       double* __restrict__ S,
                                                       float* __restrict__ h0,
                                                       float* __restrict__ partial,
                                                       int N, int gbase, int pullBlocks){
  __shared__ __align__(16) float smem[6400];   // GEMM tiles; pull1 uses first 8KB as double rd
  const int t = threadIdx.x;

  if ((int)blockIdx.x < pullBlocks){
    int i = blockIdx.x * 256 + t;
    if (PHASE == 1){
      float a = 0.f;
      int dgi = 0, br = 0;
      bool valid = i < 2 * N;
      if (valid){
        br = i >= N;
        int o = br * N;
        int c = fill[i]; if (c > CAPW) c = CAPW;
        const unsigned short* sl = slots + (size_t)i * CAPW;
        int j = 0;
        for (; j + 7 < c; j += 8){
          int dA = sl[j], dB = sl[j+1], dC = sl[j+2], dD = sl[j+3];
          int dE = sl[j+4], dF = sl[j+5], dG = sl[j+6], dH = sl[j+7];
          a += 1.f/(float)deg[o+dA] + 1.f/(float)deg[o+dB]
             + 1.f/(float)deg[o+dC] + 1.f/(float)deg[o+dD]
             + 1.f/(float)deg[o+dE] + 1.f/(float)deg[o+dF]
             + 1.f/(float)deg[o+dG] + 1.f/(float)deg[o+dH];
        }
        for (; j < c; ++j) a += 1.f/(float)deg[o + sl[j]];
        dgi = deg[i];
        w1[i] = a;
        qa[i] = dgi > 0 ? a * (1.f/(float)dgi) : 0.f;
      }
      double* rd = (double*)smem;      // 4*256 doubles = 8KB
      bool pos = valid && dgi > 0;
      rd[0*256+t] = (pos && !br) ? 1.0 : 0.0;
      rd[1*256+t] = (pos && !br) ? (double)a : 0.0;
      rd[2*256+t] = (pos &&  br) ? 1.0 : 0.0;
      rd[3*256+t] = (pos &&  br) ? (double)a : 0.0;
      __syncthreads();
      for (int off = 128; off; off >>= 1){
        if (t < off){
          rd[t]       += rd[t+off];
          rd[256+t]   += rd[256+t+off];
          rd[512+t]   += rd[512+t+off];
          rd[768+t]   += rd[768+t+off];
        }
        __syncthreads();
      }
      if (t < 4) atomicAdd(&S[t], rd[t*256]);
      return;
    } else {
      if (i >= 2 * N) return;
      int br = i >= N;
      int o = br * N;
      int c = fill[i]; if (c > CAPW) c = CAPW;
      const unsigned short* sl = slots + (size_t)i * CAPW;
      const float* qin = (PHASE == 2) ? qa : qb;
      float a = 0.f;
      int j = 0;
      for (; j + 7 < c; j += 8){
        int dA = sl[j], dB = sl[j+1], dC = sl[j+2], dD = sl[j+3];
        int dE = sl[j+4], dF = sl[j+5], dG = sl[j+6], dH = sl[j+7];
        a += qin[o+dA] + qin[o+dB] + qin[o+dC] + qin[o+dD]
           + qin[o+dE] + qin[o+dF] + qin[o+dG] + qin[o+dH];
      }
      for (; j < c; ++j) a += qin[o + sl[j]];
      if (PHASE == 2){
        w2[i] = a;
        int dgi = deg[i];
        qb[i] = dgi > 0 ? a * (1.f/(float)dgi) : 0.f;
      } else {
        w3[i] = a;
      }
      return;
    }
  }

  // branch0 GEMM-acc role: row-tile rb in [gbase, gbase+chunk)
  int rb = (int)blockIdx.x - pullBlocks + gbase;
  gemmacc128(A0, W0, b0, h0, partial, rb, N, smem);
}

// ====== tail: branch1 full gemmred (K=64, BK=32, k=0..3) || branch0 weighted colsums (k=1..3) ======
__global__ __launch_bounds__(256) void tail_kernel(const float* __restrict__ A1,
                                                   const float* __restrict__ W1,
                                                   const float* __restrict__ bias1,
                                                   const float* __restrict__ h0,
                                                   const float* __restrict__ w1,
                                                   const float* __restrict__ w2,
                                                   const float* __restrict__ w3,
                                                   float* __restrict__ partial0,
                                                   float* __restrict__ partial1,
                                                   int N, int gg){
  __shared__ __align__(16) float smem[6400];
  float (*As)[68]   = (float(*)[68])smem;
  float (*Bs)[132]  = (float(*)[132])(smem + 2176);
  float (*red)[256] = (float(*)[256])smem;
  float (*red1)[128]= (float(*)[128])smem;
  const int t  = threadIdx.x;
  const int tx = t & 15;
  const int ty = t >> 4;

  if ((int)blockIdx.x >= gg){
    // ---- branch0 weighted colsum role (k=1..3 over stored h0) ----
    const int wb = blockIdx.x - gg;
    const int rowbase = wb << 6;
    float o[4][8];
    float wr[3][4];
    #pragma unroll
    for (int i = 0; i < 4; ++i){
      int row = rowbase + (ty << 2) + i;
      bool valid = row < N;
      float4 x0 = make_float4(0,0,0,0), x1 = make_float4(0,0,0,0);
      if (valid){
        x0 = *(const float4*)&h0[(size_t)row * HF + (tx << 2)];
        x1 = *(const float4*)&h0[(size_t)row * HF + 64 + (tx << 2)];
      }
      o[i][0]=x0.x; o[i][1]=x0.y; o[i][2]=x0.z; o[i][3]=x0.w;
      o[i][4]=x1.x; o[i][5]=x1.y; o[i][6]=x1.z; o[i][7]=x1.w;
      wr[0][i] = valid ? w1[row] : 0.f;
      wr[1][i] = valid ? w2[row] : 0.f;
      wr[2][i] = valid ? w3[row] : 0.f;
    }
    #pragma unroll
    for (int k = 0; k < 3; ++k){
      float cw[8];
      #pragma unroll
      for (int j = 0; j < 8; ++j)
        cw[j] = wr[k][0]*o[0][j] + wr[k][1]*o[1][j] + wr[k][2]*o[2][j] + wr[k][3]*o[3][j];
      __syncthreads();
      #pragma unroll
      for (int j = 0; j < 4; ++j){
        red1[ty][(tx << 2) + j]      = cw[j];
        red1[ty][64 + (tx << 2) + j] = cw[4 + j];
      }
      __syncthreads();
      for (int off = 8; off; off >>= 1){
        if (ty < off){
          #pragma unroll
          for (int j = 0; j < 4; ++j){
            red1[ty][(tx << 2) + j]      += red1[ty + off][(tx << 2) + j];
            red1[ty][64 + (tx << 2) + j] += red1[ty + off][64 + (tx << 2) + j];
          }
        }
        __syncthreads();
      }
      if (ty == 0){
        #pragma unroll
        for (int j = 0; j < 4; ++j){
          partial0[(size_t)wb * 512 + (k + 1) * 128 + (tx << 2) + j]      = red1[0][(tx << 2) + j];
          partial0[(size_t)wb * 512 + (k + 1) * 128 + 64 + (tx << 2) + j] = red1[0][64 + (tx << 2) + j];
        }
      }
      __syncthreads();
    }
    return;
  }

  // ---- branch1 full gemmred role (K=64, BK=32, conflict-free) ----
  const int rb = (int)blockIdx.x;
  const int rowbase = rb << 6;
  float acc[4][8];
  #pragma unroll
  for (int i = 0; i < 4; ++i)
    #pragma unroll
    for (int j = 0; j < 8; ++j) acc[i][j] = 0.f;

  const int ar = t >> 2;
  const int ac = (t & 3) << 2;
  const int arow = rowbase + ar;
  const int bk0 = t >> 5;
  const int bc0 = (t & 31) << 2;

  for (int k0 = 0; k0 < 64; k0 += 32){
    __syncthreads();
    float4 av0 = make_float4(0.f,0.f,0.f,0.f), av1 = make_float4(0.f,0.f,0.f,0.f);
    if (arow < N){
      av0 = *(const float4*)&A1[(size_t)arow * 64 + (k0 + ac)];
      av1 = *(const float4*)&A1[(size_t)arow * 64 + (k0 + 16 + ac)];
    }
    As[ac + 0][ar]      = av0.x; As[ac + 1][ar]      = av0.y;
    As[ac + 2][ar]      = av0.z; As[ac + 3][ar]      = av0.w;
    As[16 + ac + 0][ar] = av1.x; As[16 + ac + 1][ar] = av1.y;
    As[16 + ac + 2][ar] = av1.z; As[16 + ac + 3][ar] = av1.w;
    #pragma unroll
    for (int r = 0; r < 4; ++r)
      *(float4*)&Bs[bk0 + 8*r][bc0] =
        *(const float4*)&W1[(size_t)(k0 + bk0 + 8*r) * HF + bc0];
    __syncthreads();
    #pragma unroll
    for (int kk = 0; kk < 32; ++kk){
      const float4 a  = *(const float4*)&As[kk][ty << 2];
      const float4 p0 = *(const float4*)&Bs[kk][tx << 2];
      const float4 p1 = *(const float4*)&Bs[kk][64 + (tx << 2)];
      const float aa[4] = {a.x, a.y, a.z, a.w};
      const float bb[8] = {p0.x, p0.y, p0.z, p0.w, p1.x, p1.y, p1.z, p1.w};
      #pragma unroll
      for (int i = 0; i < 4; ++i)
        #pragma unroll
        for (int j = 0; j < 8; ++j)
          acc[i][j] = fmaf(aa[i], bb[j], acc[i][j]);
    }
  }

  const float4 bia0 = *(const float4*)&bias1[tx << 2];
  const float4 bia1 = *(const float4*)&bias1[64 + (tx << 2)];
  const float bb0[8] = {bia0.x, bia0.y, bia0.z, bia0.w, bia1.x, bia1.y, bia1.z, bia1.w};
  float o[4][8];
  float wr[4][4];
  #pragma unroll
  for (int i = 0; i < 4; ++i){
    int row = rowbase + (ty << 2) + i;
    bool valid = row < N;
    #pragma unroll
    for (int j = 0; j < 8; ++j)
      o[i][j] = 0.125f * __cosf(acc[i][j] + bb0[j]);
    wr[0][i] = valid ? 1.f : 0.f;
    wr[1][i] = valid ? w1[N + row] : 0.f;
    wr[2][i] = valid ? w2[N + row] : 0.f;
    wr[3][i] = valid ? w3[N + row] : 0.f;
  }
  __syncthreads();
  #pragma unroll
  for (int kp = 0; kp < 2; ++kp){
    const int kA = kp * 2, kB = kp * 2 + 1;
    float cwA[8], cwB[8];
    #pragma unroll
    for (int j = 0; j < 8; ++j){
      cwA[j] = wr[kA][0]*o[0][j] + wr[kA][1]*o[1][j] + wr[kA][2]*o[2][j] + wr[kA][3]*o[3][j];
      cwB[j] = wr[kB][0]*o[0][j] + wr[kB][1]*o[1][j] + wr[kB][2]*o[2][j] + wr[kB][3]*o[3][j];
    }
    #pragma unroll
    for (int j = 0; j < 4; ++j){
      red[ty][(tx << 2) + j]        = cwA[j];
      red[ty][64 + (tx << 2) + j]   = cwA[4 + j];
      red[ty][128 + (tx << 2) + j]  = cwB[j];
      red[ty][192 + (tx << 2) + j]  = cwB[4 + j];
    }
    __syncthreads();
    for (int off = 8; off; off >>= 1){
      if (ty < off){
        #pragma unroll
        for (int j = 0; j < 4; ++j){
          red[ty][(tx << 2) + j]       += red[ty + off][(tx << 2) + j];
          red[ty][64 + (tx << 2) + j]  += red[ty + off][64 + (tx << 2) + j];
          red[ty][128 + (tx << 2) + j] += red[ty + off][128 + (tx << 2) + j];
          red[ty][192 + (tx << 2) + j] += red[ty + off][192 + (tx << 2) + j];
        }
      }
      __syncthreads();
    }
    if (ty == 0){
      #pragma unroll
      for (int j = 0; j < 4; ++j){
        partial1[(size_t)rb * 512 + kA * 128 + (tx << 2) + j]      = red[0][(tx << 2) + j];
        partial1[(size_t)rb * 512 + kA * 128 + 64 + (tx << 2) + j] = red[0][64 + (tx << 2) + j];
        partial1[(size_t)rb * 512 + kB * 128 + (tx << 2) + j]      = red[0][128 + (tx << 2) + j];
        partial1[(size_t)rb * 512 + kB * 128 + 64 + (tx << 2) + j] = red[0][192 + (tx << 2) + j];
      }
    }
    __syncthreads();
  }
}

// G[br][t] += sum_b partial[br][b][t]  (fp64), blockIdx.y = branch
__global__ __launch_bounds__(512) void greduce_kernel(const float* __restrict__ partial,
                                                      double* __restrict__ G, int nb, int stride){
  int br = blockIdx.y;
  const float* p = partial + (size_t)br * stride;
  double* Gb = G + 512 * br;
  int t = threadIdx.x;
  double s = 0.0;
  for (int b = blockIdx.x; b < nb; b += gridDim.x) s += (double)p[(size_t)b * 512 + t];
  atomicAdd(&Gb[t], s);
}

// ---------------- moment recursion head, LDS-staged weights ----------------
__global__ __launch_bounds__(512) void head_kernel(const double* __restrict__ G,
                                                   const double* __restrict__ S,
                                                   const float* __restrict__ WsA, const float* __restrict__ WnA, const float* __restrict__ bA,
                                                   const float* __restrict__ WsB, const float* __restrict__ WnB, const float* __restrict__ bB,
                                                   float* __restrict__ ymean, int n){
  const int br = blockIdx.x;
  const double* Gb = G + 512 * br;
  const double* Sb = S + 2 * br;
  const float* Ws   = br ? WsB : WsA;
  const float* Wn   = br ? WnB : WnA;
  const float* bias = br ? bB  : bA;
  float* yout = ymean + 128 * br;

  __shared__ double g[4][128], ng[3][128];
  __shared__ float lws[32][128], lwn[32][128];
  const int t = threadIdx.x;
  const int k = t >> 7, j = t & 127;
  g[k][j] = Gb[t];
  double s[4];
  s[0] = (double)n; s[1] = Sb[0]; s[2] = Sb[1]; s[3] = 0.0;

  for (int i = 0; i < 3; ++i){
    const float* ws = Ws + (size_t)i * 16384;
    const float* wn = Wn + (size_t)i * 16384;
    const float* bi = bias + (size_t)i * 128;
    const int kmax = 2 - i;
    double a = (k <= kmax) ? s[k] * (double)bi[j] : 0.0;
    for (int mc = 0; mc < 128; mc += 32){
      __syncthreads();
      #pragma unroll
      for (int pp = 0; pp < 2; ++pp){
        int idx = (pp * 512 + t) << 2;
        int mm = idx >> 7, cc = idx & 127;
        *(float4*)&lws[mm][cc] = *(const float4*)&ws[(size_t)(mc + mm) * 128 + cc];
        *(float4*)&lwn[mm][cc] = *(const float4*)&wn[(size_t)(mc + mm) * 128 + cc];
      }
      __syncthreads();
      if (k <= kmax){
        #pragma unroll
        for (int m = 0; m < 32; ++m){
          a += g[k][mc + m]     * (double)lws[m][j];
          a += g[k + 1][mc + m] * (double)lwn[m][j];
        }
      }
    }
    __syncthreads();
    if (k <= kmax) ng[k][j] = a;
    __syncthreads();
    if (k <= kmax) g[k][j] = ng[k][j];
  }
  __syncthreads();
  if (t < 128) yout[t] = (float)(g[0][t] / (double)n);
}

// ---------------- final MLP ----------------
__global__ void final_kernel(const float* __restrict__ ymean,
                             const float* __restrict__ fc1W, const float* __restrict__ fc1b,
                             const float* __restrict__ outW, const float* __restrict__ outb,
                             const float* __restrict__ roW, const float* __restrict__ rob,
                             float* __restrict__ out){
  __shared__ float y[256], h1[128], h2[64];
  int t = threadIdx.x;
  y[t] = ymean[t];
  __syncthreads();
  if (t < 128){
    float a = fc1b[t];
    for (int k = 0; k < 256; ++k) a = fmaf(y[k], fc1W[k * 128 + t], a);
    h1[t] = a > 0.f ? a : 0.f;
  }
  __syncthreads();
  if (t < 64){
    float a = outb[t];
    for (int k = 0; k < 128; ++k) a = fmaf(h1[k], outW[k * 64 + t], a);
    h2[t] = a > 0.f ? a : 0.01f * a;
  }
  __syncthreads();
  if (t == 0){
    float a = rob[0];
    for (int k = 0; k < 64; ++k) a = fmaf(h2[k], roW[k], a);
    out[0] = a;
  }
}

extern "C" void kernel_launch(void* const* d_in, const int* in_sizes, int n_in,
                              void* d_out, int out_size, void* d_ws, size_t ws_size,
                              hipStream_t stream){
  const float* feat0  = (const float*)d_in[0];
  const float* feat1  = (const float*)d_in[1];
  const int*   src0   = (const int*)d_in[2];
  const int*   dst0   = (const int*)d_in[3];
  const int*   src1   = (const int*)d_in[4];
  const int*   dst1   = (const int*)d_in[5];
  const float* rbfW0  = (const float*)d_in[6];
  const float* rbfb0  = (const float*)d_in[7];
  const float* rbfW1  = (const float*)d_in[8];
  const float* rbfb1  = (const float*)d_in[9];
  const float* Wself1 = (const float*)d_in[10];
  const float* Wneigh1= (const float*)d_in[11];
  const float* b1     = (const float*)d_in[12];
  const float* Wself2 = (const float*)d_in[13];
  const float* Wneigh2= (const float*)d_in[14];
  const float* b2     = (const float*)d_in[15];
  const float* fc1W   = (const float*)d_in[16];
  const float* fc1b   = (const float*)d_in[17];
  const float* outW   = (const float*)d_in[18];
  const float* outb   = (const float*)d_in[19];
  const float* roW    = (const float*)d_in[20];
  const float* rob    = (const float*)d_in[21];

  const int N = in_sizes[0] / 128;   // feat0 is [N,128]
  const int E = in_sizes[2];
  const int HW = (N + 3) >> 2;

  char* w = (char*)d_ws;
  size_t off = 0;
  auto alloc = [&](size_t bytes) -> char* {
    char* p = w + off; off += (bytes + 255) & ~(size_t)255; return p;
  };
  int*    deg    = (int*)   alloc((size_t)2 * N * 4);
  int*    fill   = (int*)   alloc((size_t)2 * N * 4);
  float*  w1     = (float*) alloc((size_t)2 * N * 4);
  float*  w2     = (float*) alloc((size_t)2 * N * 4);
  float*  w3     = (float*) alloc((size_t)2 * N * 4);
  float*  qa     = (float*) alloc((size_t)2 * N * 4);
  float*  qb     = (float*) alloc((size_t)2 * N * 4);
  double* S      = (double*)alloc(4 * sizeof(double));     // pads to 256 B = 32 doubles
  double* G      = (double*)alloc(1024 * sizeof(double));  // contiguous after padded S
  float*  ymean  = (float*) alloc(256 * sizeof(float));
  const int gg   = (N + 63) >> 6;
  float*  partial= (float*) alloc((size_t)2 * gg * 512 * 4);          // [branch][gg][512]
  float*  h0buf  = (float*) alloc((size_t)N * HF * 4);                // 25.6 MB (branch0 h)
  unsigned short* slots = (unsigned short*)alloc((size_t)2 * N * CAPW * 2);  // 12.8 MB
  unsigned int* cntbuf  = (unsigned int*)alloc((size_t)4 * HB * HW * 4);     // 12.8 MB

  const int nGrid2 = (2 * N + 255) >> 8;
  const int ch = (gg + 2) / 3;                    // branch0 acc chunk per pull phase
  const int c0 = 0, c1 = ch, c2 = 2 * ch;
  const int n0 = ch, n1 = (2*ch > gg ? gg - ch : ch), n2 = gg - 2 * ch;

  // build: hist -> scan -> scatter
  hist_kernel<<<256, 256, 0, stream>>>(src0, dst0, src1, dst1, cntbuf, N, E);
  scan_kernel<<<nGrid2, 256, 0, stream>>>(cntbuf, deg, fill, S, N);
  scatter_kernel<<<256, 256, 0, stream>>>(src0, dst0, src1, dst1, cntbuf, slots, N, E);
  // pulls overlapped with branch0 GEMM-acc chunks (acc independent of w's)
  pullgemm_kernel<1><<<nGrid2 + n0, 256, 0, stream>>>(feat0, rbfW0, rbfb0, slots, fill, deg,
                                                      w1, qa, qb, w2, w3, S, h0buf, partial,
                                                      N, c0, nGrid2);
  pullgemm_kernel<2><<<nGrid2 + n1, 256, 0, stream>>>(feat0, rbfW0, rbfb0, slots, fill, deg,
                                                      w1, qa, qb, w2, w3, S, h0buf, partial,
                                                      N, c1, nGrid2);
  pullgemm_kernel<3><<<nGrid2 + n2, 256, 0, stream>>>(feat0, rbfW0, rbfb0, slots, fill, deg,
                                                      w1, qa, qb, w2, w3, S, h0buf, partial,
                                                      N, c2, nGrid2);
  // tail: branch1 full gemmred || branch0 weighted colsums over h0
  tail_kernel<<<2 * gg, 256, 0, stream>>>(feat1, rbfW1, rbfb1, h0buf, w1, w2, w3,
                                          partial, partial + (size_t)gg * 512, N, gg);
  greduce_kernel<<<dim3(16, 2), 512, 0, stream>>>(partial, G, gg, gg * 512);
  head_kernel<<<2, 512, 0, stream>>>(G, S, Wself2, Wneigh2, b2, Wself1, Wneigh1, b1, ymean, N);
  final_kernel<<<1, 256, 0, stream>>>(ymean, fc1W, fc1b, outW, outb, roW, rob, (float*)d_out);
}

// Round 22
// 196.978 us; speedup vs baseline: 1.0405x; 1.0405x over previous
//
#include <hip/hip_runtime.h>
#include <math.h>

#define HF   128  // hidden width
#define CAPW 64   // ushort slots per node (Poisson(16): P(outdeg>64) ~ 1e-18)
#define HB   64   // hist blocks per (branch, keytype)

// ================= phase 1: block-private LDS histograms (1-pass, 50KB) =================
__global__ __launch_bounds__(256) void hist_kernel(const int* __restrict__ s0, const int* __restrict__ d0,
                                                   const int* __restrict__ s1, const int* __restrict__ d1,
                                                   unsigned int* __restrict__ cntbuf,
                                                   int N, int E){
  __shared__ unsigned int sm32[12544];                 // 50176 B >= N bytes
  const int t = threadIdx.x;
  const int HW = (N + 3) >> 2;
  const int b  = blockIdx.x & 63;
  const int br = (blockIdx.x >> 6) & 1;
  const int z  = blockIdx.x >> 7;
  const int* keys = z ? (br ? d1 : d0) : (br ? s1 : s0);
  for (int w = t; w < HW; w += 256) sm32[w] = 0u;
  __syncthreads();
  const int C  = (E + HB - 1) / HB;
  const int lo = b * C;
  int hi = lo + C; if (hi > E) hi = E;
  for (int i = lo + t; i < hi; i += 256){
    int k = keys[i];
    atomicAdd(&sm32[k >> 2], 1u << ((k & 3) << 3));
  }
  __syncthreads();
  unsigned int* out = cntbuf + ((size_t)(z * 2 + br) * HB + b) * HW;
  for (int w = t; w < HW; w += 256) out[w] = sm32[w];
}

// ====== phase 2: per-key reduce + prefix (no atomics); block 0 zeroes S+G (full padded span) ======
__global__ __launch_bounds__(256) void scan_kernel(unsigned int* __restrict__ cntbuf,
                                                   int* __restrict__ deg,
                                                   int* __restrict__ fill,
                                                   double* __restrict__ SG, int N){
  if (blockIdx.x == 0){
    // S pads to 256 B (32 doubles) before G(1024 doubles): zero 32+1024 = 1056 doubles.
    for (int z = threadIdx.x; z < 1056; z += 256) SG[z] = 0.0;
  }
  int k = blockIdx.x * 256 + threadIdx.x;
  if (k >= 2 * N) return;
  const int br = k >= N;
  const int kk = k - br * N;
  const int HW = (N + 3) >> 2;
  unsigned char* cb = (unsigned char*)cntbuf;
  size_t dbase = ((size_t)(2 + br) * HB) * HW * 4 + kk;
  int ds = 0;
  for (int b = 0; b < HB; ++b) ds += cb[dbase + (size_t)b * HW * 4];
  deg[k] = ds;
  size_t sbase = ((size_t)(0 + br) * HB) * HW * 4 + kk;
  int run = 0;
  for (int b = 0; b < HB; ++b){
    size_t a = sbase + (size_t)b * HW * 4;
    int c = cb[a];
    cb[a] = (unsigned char)run;
    run += c;
  }
  fill[k] = run;
}

// ================= phase 3: scatter, 256 blocks via key-range halves (25KB LDS) =================
__global__ __launch_bounds__(256) void scatter_kernel(const int* __restrict__ s0, const int* __restrict__ d0,
                                                      const int* __restrict__ s1, const int* __restrict__ d1,
                                                      const unsigned int* __restrict__ cntbuf,
                                                      unsigned short* __restrict__ slots,
                                                      int N, int E){
  __shared__ unsigned int sm32[6272];                  // 25088 B: half-range offsets
  const int t  = threadIdx.x;
  const int b  = blockIdx.x & 63;
  const int br = (blockIdx.x >> 6) & 1;
  const int h  = blockIdx.x >> 7;
  const int HW = (N + 3) >> 2;
  const int HN = ((N + 7) >> 3) << 2;                  // keys in half 0 (multiple of 4)
  const int klo = h ? HN : 0;
  const int khi = h ? N : HN;
  const int nw  = (khi - klo + 3) >> 2;
  const unsigned int* offw = cntbuf + ((size_t)br * HB + b) * HW + (klo >> 2);
  for (int w = t; w < nw; w += 256) sm32[w] = offw[w];
  __syncthreads();
  const int* srcA = br ? s1 : s0;
  const int* dstA = br ? d1 : d0;
  const int C  = (E + HB - 1) / HB;
  const int lo = b * C;
  int hi = lo + C; if (hi > E) hi = E;
  const size_t obase = (size_t)br * N;
  for (int i = lo + t; i < hi; i += 256){
    int s = srcA[i];
    if (s < klo || s >= khi) continue;
    int d = dstA[i];
    int sl = s - klo;
    unsigned int old = atomicAdd(&sm32[sl >> 2], 1u << ((sl & 3) << 3));
    int j = (old >> ((sl & 3) << 3)) & 0xff;
    if (j < CAPW) slots[(obase + s) * CAPW + j] = (unsigned short)d;
  }
}

// ---------------- pull1: w1 = P^T 1 (1/deg inline), qa = w1/deg, fused s1/s2 reduction ----------------
__global__ __launch_bounds__(256) void pull1_kernel(const unsigned short* __restrict__ slots,
                                                    const int* __restrict__ fill,
                                                    const int* __restrict__ deg,
                                                    float* __restrict__ w1,
                                                    float* __restrict__ qa,
                                                    double* __restrict__ S, int N){
  int i = blockIdx.x * 256 + threadIdx.x;
  int t = threadIdx.x;
  float a = 0.f;
  int dgi = 0;
  int br = 0;
  bool valid = i < 2 * N;
  if (valid){
    br = i >= N;
    int o = br * N;
    int c = fill[i]; if (c > CAPW) c = CAPW;
    const unsigned short* sl = slots + (size_t)i * CAPW;
    int j = 0;
    for (; j + 7 < c; j += 8){
      int dA = sl[j], dB = sl[j+1], dC = sl[j+2], dD = sl[j+3];
      int dE = sl[j+4], dF = sl[j+5], dG = sl[j+6], dH = sl[j+7];
      a += 1.f/(float)deg[o+dA] + 1.f/(float)deg[o+dB]
         + 1.f/(float)deg[o+dC] + 1.f/(float)deg[o+dD]
         + 1.f/(float)deg[o+dE] + 1.f/(float)deg[o+dF]
         + 1.f/(float)deg[o+dG] + 1.f/(float)deg[o+dH];
    }
    for (; j < c; ++j) a += 1.f/(float)deg[o + sl[j]];
    dgi = deg[i];
    w1[i] = a;
    qa[i] = dgi > 0 ? a * (1.f/(float)dgi) : 0.f;
  }
  __shared__ double rd[4][256];
  bool pos = valid && dgi > 0;
  rd[0][t] = (pos && !br) ? 1.0 : 0.0;
  rd[1][t] = (pos && !br) ? (double)a : 0.0;
  rd[2][t] = (pos &&  br) ? 1.0 : 0.0;
  rd[3][t] = (pos &&  br) ? (double)a : 0.0;
  __syncthreads();
  for (int off = 128; off; off >>= 1){
    if (t < off){
      rd[0][t] += rd[0][t+off]; rd[1][t] += rd[1][t+off];
      rd[2][t] += rd[2][t+off]; rd[3][t] += rd[3][t+off];
    }
    __syncthreads();
  }
  if (t < 4) atomicAdd(&S[t], rd[t][0]);
}

// ---------------- pull2/3: w = gather(qin); optional q = w/deg ----------------
template<bool WQ>
__global__ __launch_bounds__(256) void pull_kernel(const unsigned short* __restrict__ slots,
                                                   const int* __restrict__ fill,
                                                   const int* __restrict__ deg,
                                                   const float* __restrict__ qin,
                                                   float* __restrict__ wout,
                                                   float* __restrict__ qout, int N){
  int i = blockIdx.x * 256 + threadIdx.x;
  if (i >= 2 * N) return;
  int br = i >= N;
  int o = br * N;
  int c = fill[i]; if (c > CAPW) c = CAPW;
  const unsigned short* sl = slots + (size_t)i * CAPW;
  float a = 0.f;
  int j = 0;
  for (; j + 7 < c; j += 8){
    int dA = sl[j], dB = sl[j+1], dC = sl[j+2], dD = sl[j+3];
    int dE = sl[j+4], dF = sl[j+5], dG = sl[j+6], dH = sl[j+7];
    a += qin[o+dA] + qin[o+dB] + qin[o+dC] + qin[o+dD]
       + qin[o+dE] + qin[o+dF] + qin[o+dG] + qin[o+dH];
  }
  for (; j < c; ++j) a += qin[o + sl[j]];
  wout[i] = a;
  if (WQ){
    int dgi = deg[i];
    qout[i] = dgi > 0 ? a * (1.f/(float)dgi) : 0.f;
  }
}

// ====== fused RBF GEMM + 4 weighted column-sums, 64x128 tile, BK=32, conflict-free staging ======
template<int K1>
__device__ __forceinline__ void gemmred_body(const float* __restrict__ A,
                                             const float* __restrict__ W,
                                             const float* __restrict__ bias,
                                             const float* __restrict__ w1,
                                             const float* __restrict__ w2,
                                             const float* __restrict__ w3,
                                             int wo, float* __restrict__ partial,
                                             int rb, int N,
                                             float (*As)[68], float (*Bs)[132], float (*red)[256]){
  const int t  = threadIdx.x;
  const int tx = t & 15;
  const int ty = t >> 4;
  const int rowbase = rb << 6;

  float acc[4][8];
  #pragma unroll
  for (int i = 0; i < 4; ++i)
    #pragma unroll
    for (int j = 0; j < 8; ++j) acc[i][j] = 0.f;

  // A staging: ar=t>>2 (0..63), ac=(t&3)<<2 (0,4,8,12); column groups {k0+ac, k0+16+ac}
  const int ar = t >> 2;
  const int ac = (t & 3) << 2;
  const int arow = rowbase + ar;
  // B staging: bk0=t>>5 (0..7), bc0=(t&31)<<2; rows bk0+8r, r=0..3
  const int bk0 = t >> 5;
  const int bc0 = (t & 31) << 2;

  for (int k0 = 0; k0 < K1; k0 += 32){
    __syncthreads();
    float4 av0 = make_float4(0.f,0.f,0.f,0.f), av1 = make_float4(0.f,0.f,0.f,0.f);
    if (arow < N){
      av0 = *(const float4*)&A[(size_t)arow * K1 + (k0 + ac)];
      av1 = *(const float4*)&A[(size_t)arow * K1 + (k0 + 16 + ac)];
    }
    As[ac + 0][ar]      = av0.x; As[ac + 1][ar]      = av0.y;
    As[ac + 2][ar]      = av0.z; As[ac + 3][ar]      = av0.w;
    As[16 + ac + 0][ar] = av1.x; As[16 + ac + 1][ar] = av1.y;
    As[16 + ac + 2][ar] = av1.z; As[16 + ac + 3][ar] = av1.w;
    #pragma unroll
    for (int r = 0; r < 4; ++r)
      *(float4*)&Bs[bk0 + 8*r][bc0] =
        *(const float4*)&W[(size_t)(k0 + bk0 + 8*r) * HF + bc0];
    __syncthreads();
    #pragma unroll
    for (int kk = 0; kk < 32; ++kk){
      const float4 a  = *(const float4*)&As[kk][ty << 2];
      const float4 p0 = *(const float4*)&Bs[kk][tx << 2];
      const float4 p1 = *(const float4*)&Bs[kk][64 + (tx << 2)];
      const float aa[4] = {a.x, a.y, a.z, a.w};
      const float bb[8] = {p0.x, p0.y, p0.z, p0.w, p1.x, p1.y, p1.z, p1.w};
      #pragma unroll
      for (int i = 0; i < 4; ++i)
        #pragma unroll
        for (int j = 0; j < 8; ++j)
          acc[i][j] = fmaf(aa[i], bb[j], acc[i][j]);
    }
  }

  const float4 bia0 = *(const float4*)&bias[tx << 2];
  const float4 bia1 = *(const float4*)&bias[64 + (tx << 2)];
  const float bb0[8] = {bia0.x, bia0.y, bia0.z, bia0.w, bia1.x, bia1.y, bia1.z, bia1.w};
  float o[4][8];
  float wr[4][4];
  #pragma unroll
  for (int i = 0; i < 4; ++i){
    int row = rowbase + (ty << 2) + i;
    bool valid = row < N;
    #pragma unroll
    for (int j = 0; j < 8; ++j)
      o[i][j] = 0.125f * __cosf(acc[i][j] + bb0[j]);   // native v_cos (abs err ~1e-6, |x|<~40)
    wr[0][i] = valid ? 1.f : 0.f;
    wr[1][i] = valid ? w1[wo + row] : 0.f;
    wr[2][i] = valid ? w2[wo + row] : 0.f;
    wr[3][i] = valid ? w3[wo + row] : 0.f;
  }
  __syncthreads();   // As/Bs dead; red overlays them
  #pragma unroll
  for (int kp = 0; kp < 2; ++kp){
    const int kA = kp * 2, kB = kp * 2 + 1;
    float cwA[8], cwB[8];
    #pragma unroll
    for (int j = 0; j < 8; ++j){
      cwA[j] = wr[kA][0]*o[0][j] + wr[kA][1]*o[1][j] + wr[kA][2]*o[2][j] + wr[kA][3]*o[3][j];
      cwB[j] = wr[kB][0]*o[0][j] + wr[kB][1]*o[1][j] + wr[kB][2]*o[2][j] + wr[kB][3]*o[3][j];
    }
    #pragma unroll
    for (int j = 0; j < 4; ++j){
      red[ty][(tx << 2) + j]        = cwA[j];
      red[ty][64 + (tx << 2) + j]   = cwA[4 + j];
      red[ty][128 + (tx << 2) + j]  = cwB[j];
      red[ty][192 + (tx << 2) + j]  = cwB[4 + j];
    }
    __syncthreads();
    for (int off = 8; off; off >>= 1){
      if (ty < off){
        #pragma unroll
        for (int j = 0; j < 4; ++j){
          red[ty][(tx << 2) + j]       += red[ty + off][(tx << 2) + j];
          red[ty][64 + (tx << 2) + j]  += red[ty + off][64 + (tx << 2) + j];
          red[ty][128 + (tx << 2) + j] += red[ty + off][128 + (tx << 2) + j];
          red[ty][192 + (tx << 2) + j] += red[ty + off][192 + (tx << 2) + j];
        }
      }
      __syncthreads();
    }
    if (ty == 0){
      #pragma unroll
      for (int j = 0; j < 4; ++j){
        partial[(size_t)rb * 512 + kA * 128 + (tx << 2) + j]      = red[0][(tx << 2) + j];
        partial[(size_t)rb * 512 + kA * 128 + 64 + (tx << 2) + j] = red[0][64 + (tx << 2) + j];
        partial[(size_t)rb * 512 + kB * 128 + (tx << 2) + j]      = red[0][128 + (tx << 2) + j];
        partial[(size_t)rb * 512 + kB * 128 + 64 + (tx << 2) + j] = red[0][192 + (tx << 2) + j];
      }
    }
    __syncthreads();
  }
}

__global__ __launch_bounds__(256) void gemmred2_kernel(const float* __restrict__ A0,
                                                       const float* __restrict__ W0,
                                                       const float* __restrict__ b0,
                                                       const float* __restrict__ A1,
                                                       const float* __restrict__ W1,
                                                       const float* __restrict__ b1,
                                                       const float* __restrict__ w1,
                                                       const float* __restrict__ w2,
                                                       const float* __restrict__ w3,
                                                       float* __restrict__ partial,
                                                       int N, int gg){
  __shared__ __align__(16) float smem[6400];   // As[32][68]+Bs[32][132]=6400; red[16][256] overlays
  float (*As)[68]   = (float(*)[68])smem;
  float (*Bs)[132]  = (float(*)[132])(smem + 2176);
  float (*red)[256] = (float(*)[256])smem;
  if ((int)blockIdx.x < gg)
    gemmred_body<128>(A0, W0, b0, w1, w2, w3, 0, partial, blockIdx.x, N, As, Bs, red);
  else
    gemmred_body<64>(A1, W1, b1, w1, w2, w3, N, partial + (size_t)gg * 512,
                     blockIdx.x - gg, N, As, Bs, red);
}

// G[br][t] += sum_b partial[br][b][t]  (fp64), blockIdx.y = branch
__global__ __launch_bounds__(512) void greduce_kernel(const float* __restrict__ partial,
                                                      double* __restrict__ G, int nb, int stride){
  int br = blockIdx.y;
  const float* p = partial + (size_t)br * stride;
  double* Gb = G + 512 * br;
  int t = threadIdx.x;
  double s = 0.0;
  for (int b = blockIdx.x; b < nb; b += gridDim.x) s += (double)p[(size_t)b * 512 + t];
  atomicAdd(&Gb[t], s);
}

// ---------------- moment recursion head, LDS-staged weights ----------------
__global__ __launch_bounds__(512) void head_kernel(const double* __restrict__ G,
                                                   const double* __restrict__ S,
                                                   const float* __restrict__ WsA, const float* __restrict__ WnA, const float* __restrict__ bA,
                                                   const float* __restrict__ WsB, const float* __restrict__ WnB, const float* __restrict__ bB,
                                                   float* __restrict__ ymean, int n){
  const int br = blockIdx.x;
  const double* Gb = G + 512 * br;
  const double* Sb = S + 2 * br;
  const float* Ws   = br ? WsB : WsA;
  const float* Wn   = br ? WnB : WnA;
  const float* bias = br ? bB  : bA;
  float* yout = ymean + 128 * br;

  __shared__ double g[4][128], ng[3][128];
  __shared__ float lws[32][128], lwn[32][128];
  const int t = threadIdx.x;
  const int k = t >> 7, j = t & 127;
  g[k][j] = Gb[t];
  double s[4];
  s[0] = (double)n; s[1] = Sb[0]; s[2] = Sb[1]; s[3] = 0.0;

  for (int i = 0; i < 3; ++i){
    const float* ws = Ws + (size_t)i * 16384;
    const float* wn = Wn + (size_t)i * 16384;
    const float* bi = bias + (size_t)i * 128;
    const int kmax = 2 - i;
    double a = (k <= kmax) ? s[k] * (double)bi[j] : 0.0;
    for (int mc = 0; mc < 128; mc += 32){
      __syncthreads();
      #pragma unroll
      for (int pp = 0; pp < 2; ++pp){
        int idx = (pp * 512 + t) << 2;
        int mm = idx >> 7, cc = idx & 127;
        *(float4*)&lws[mm][cc] = *(const float4*)&ws[(size_t)(mc + mm) * 128 + cc];
        *(float4*)&lwn[mm][cc] = *(const float4*)&wn[(size_t)(mc + mm) * 128 + cc];
      }
      __syncthreads();
      if (k <= kmax){
        #pragma unroll
        for (int m = 0; m < 32; ++m){
          a += g[k][mc + m]     * (double)lws[m][j];
          a += g[k + 1][mc + m] * (double)lwn[m][j];
        }
      }
    }
    __syncthreads();
    if (k <= kmax) ng[k][j] = a;
    __syncthreads();
    if (k <= kmax) g[k][j] = ng[k][j];
  }
  __syncthreads();
  if (t < 128) yout[t] = (float)(g[0][t] / (double)n);
}

// ---------------- final MLP ----------------
__global__ void final_kernel(const float* __restrict__ ymean,
                             const float* __restrict__ fc1W, const float* __restrict__ fc1b,
                             const float* __restrict__ outW, const float* __restrict__ outb,
                             const float* __restrict__ roW, const float* __restrict__ rob,
                             float* __restrict__ out){
  __shared__ float y[256], h1[128], h2[64];
  int t = threadIdx.x;
  y[t] = ymean[t];
  __syncthreads();
  if (t < 128){
    float a = fc1b[t];
    for (int k = 0; k < 256; ++k) a = fmaf(y[k], fc1W[k * 128 + t], a);
    h1[t] = a > 0.f ? a : 0.f;
  }
  __syncthreads();
  if (t < 64){
    float a = outb[t];
    for (int k = 0; k < 128; ++k) a = fmaf(h1[k], outW[k * 64 + t], a);
    h2[t] = a > 0.f ? a : 0.01f * a;
  }
  __syncthreads();
  if (t == 0){
    float a = rob[0];
    for (int k = 0; k < 64; ++k) a = fmaf(h2[k], roW[k], a);
    out[0] = a;
  }
}

extern "C" void kernel_launch(void* const* d_in, const int* in_sizes, int n_in,
                              void* d_out, int out_size, void* d_ws, size_t ws_size,
                              hipStream_t stream){
  const float* feat0  = (const float*)d_in[0];
  const float* feat1  = (const float*)d_in[1];
  const int*   src0   = (const int*)d_in[2];
  const int*   dst0   = (const int*)d_in[3];
  const int*   src1   = (const int*)d_in[4];
  const int*   dst1   = (const int*)d_in[5];
  const float* rbfW0  = (const float*)d_in[6];
  const float* rbfb0  = (const float*)d_in[7];
  const float* rbfW1  = (const float*)d_in[8];
  const float* rbfb1  = (const float*)d_in[9];
  const float* Wself1 = (const float*)d_in[10];
  const float* Wneigh1= (const float*)d_in[11];
  const float* b1     = (const float*)d_in[12];
  const float* Wself2 = (const float*)d_in[13];
  const float* Wneigh2= (const float*)d_in[14];
  const float* b2     = (const float*)d_in[15];
  const float* fc1W   = (const float*)d_in[16];
  const float* fc1b   = (const float*)d_in[17];
  const float* outW   = (const float*)d_in[18];
  const float* outb   = (const float*)d_in[19];
  const float* roW    = (const float*)d_in[20];
  const float* rob    = (const float*)d_in[21];

  const int N = in_sizes[0] / 128;   // feat0 is [N,128]
  const int E = in_sizes[2];
  const int HW = (N + 3) >> 2;

  char* w = (char*)d_ws;
  size_t off = 0;
  auto alloc = [&](size_t bytes) -> char* {
    char* p = w + off; off += (bytes + 255) & ~(size_t)255; return p;
  };
  int*    deg    = (int*)   alloc((size_t)2 * N * 4);
  int*    fill   = (int*)   alloc((size_t)2 * N * 4);
  float*  w1     = (float*) alloc((size_t)2 * N * 4);
  float*  w2     = (float*) alloc((size_t)2 * N * 4);
  float*  w3     = (float*) alloc((size_t)2 * N * 4);
  float*  qa     = (float*) alloc((size_t)2 * N * 4);
  float*  qb     = (float*) alloc((size_t)2 * N * 4);
  double* S      = (double*)alloc(4 * sizeof(double));     // pads to 256 B = 32 doubles
  double* G      = (double*)alloc(1024 * sizeof(double));  // contiguous after padded S
  float*  ymean  = (float*) alloc(256 * sizeof(float));
  const int gg   = (N + 63) >> 6;
  float*  partial= (float*) alloc((size_t)2 * gg * 512 * 4);          // [branch][gg][512]
  unsigned short* slots = (unsigned short*)alloc((size_t)2 * N * CAPW * 2);  // 12.8 MB
  unsigned int* cntbuf  = (unsigned int*)alloc((size_t)4 * HB * HW * 4);     // 12.8 MB

  const int nGrid2 = (2 * N + 255) >> 8;

  // phase 1: LDS histograms (256 blocks, 1-pass 50KB)
  hist_kernel<<<256, 256, 0, stream>>>(src0, dst0, src1, dst1, cntbuf, N, E);
  // phase 2: per-key reduce + prefix -> deg, fill, slot offsets; zeroes S+G (1056 doubles)
  scan_kernel<<<nGrid2, 256, 0, stream>>>(cntbuf, deg, fill, S, N);
  // phase 3: scatter into slot table (256 blocks, key halves)
  scatter_kernel<<<256, 256, 0, stream>>>(src0, dst0, src1, dst1, cntbuf, slots, N, E);
  pull1_kernel<<<nGrid2, 256, 0, stream>>>(slots, fill, deg, w1, qa, S, N);          // w1 + s1/s2
  pull_kernel<true ><<<nGrid2, 256, 0, stream>>>(slots, fill, deg, qa, w2, qb, N);   // w2
  pull_kernel<false><<<nGrid2, 256, 0, stream>>>(slots, fill, deg, qb, w3, qb, N);   // w3
  // both branches' full gemmred in one dispatch (64x128 tile, BK=32, conflict-free staging)
  gemmred2_kernel<<<2 * gg, 256, 0, stream>>>(feat0, rbfW0, rbfb0, feat1, rbfW1, rbfb1,
                                              w1, w2, w3, partial, N, gg);
  greduce_kernel<<<dim3(16, 2), 512, 0, stream>>>(partial, G, gg, gg * 512);
  head_kernel<<<2, 512, 0, stream>>>(G, S, Wself2, Wneigh2, b2, Wself1, Wneigh1, b1, ymean, N);
  final_kernel<<<1, 256, 0, stream>>>(ymean, fc1W, fc1b, outW, outb, roW, rob, (float*)d_out);
}